// Round 12
// baseline (213.013 us; speedup 1.0000x reference)
//
#include <hip/hip_runtime.h>

// ---------- problem constants ----------
#define M_TOT 16384   // B*S = 32*512
#define N_TOT 4096    // OUT
#define K_TOT 1024    // IN
#define R_LORA 16
#define NSTEP 64      // 4 tm-tiles x 16 K-tiles, persistent single-phase pipeline

#define AT_LDE 1036   // padded At row stride (elems): breaks 8-way bank pattern

typedef __attribute__((ext_vector_type(8))) short bf16x8_t;
typedef __attribute__((ext_vector_type(4))) float f32x4_t;

__device__ __forceinline__ unsigned short f2bf(float f) {
  unsigned u = __builtin_bit_cast(unsigned, f);
  u += 0x7FFFu + ((u >> 16) & 1u);
  return (unsigned short)(u >> 16);
}

__device__ __forceinline__ void gload_lds16(const void* g, void* l) {
  __builtin_amdgcn_global_load_lds(
      (const __attribute__((address_space(1))) unsigned int*)g,
      (__attribute__((address_space(3))) unsigned int*)l, 16, 0, 0);
}

// ---------- fused prep: ONE launch, 4 independent job ranges ----------
// bid [0,1024):    x f32 -> bf16 stream (xB)
// bid [1024,2048): Wt[n][k] = bf16(W[k][n]) tiled transpose
// bid [2048,2304): lbT[aid][n][r] = bf16(lora_b[aid][r][n])
// bid [2304,2560): low_rank via MFMA reading x f32 DIRECTLY (no xB/AtB dep)
__global__ __launch_bounds__(256) void prep_kernel(const float* __restrict__ x,
                                                   const float* __restrict__ W,
                                                   const float* __restrict__ lora_a,
                                                   const float* __restrict__ lora_b,
                                                   const int* __restrict__ aids,
                                                   unsigned short* __restrict__ xB,
                                                   unsigned short* __restrict__ WtB,
                                                   unsigned short* __restrict__ lrB,
                                                   unsigned short* __restrict__ lbT) {
  __shared__ char prep_smem[16 * AT_LDE * 2 + 128];  // At 33.2 KB (aliased by job B)
  const int bid = blockIdx.x;
  const int t = threadIdx.x;

  if (bid < 1024) {
    // ===== job A: x fp32 -> bf16 stream =====
    size_t i = (size_t)bid * 256 + t;
    const size_t stride = (size_t)1024 * 256;
    const size_t n4 = (size_t)M_TOT * K_TOT / 4;
    for (; i < n4; i += stride) {
      float4 v = ((const float4*)x)[i];
      ushort4 h;
      h.x = f2bf(v.x); h.y = f2bf(v.y); h.z = f2bf(v.z); h.w = f2bf(v.w);
      ((ushort4*)xB)[i] = h;
    }
  } else if (bid < 2048) {
    // ===== job B: W transpose =====
    float (*lds)[65] = (float(*)[65])prep_smem;
    const int v = bid - 1024;
    const int k0 = (v & 15) * 64;
    const int n0 = (v >> 4) * 64;
    const int rr = t >> 4;
    const int cc = (t & 15) * 4;
#pragma unroll
    for (int i = 0; i < 4; ++i) {
      int row = i * 16 + rr;
      float4 w4 = *(const float4*)(W + (size_t)(k0 + row) * N_TOT + n0 + cc);
      lds[row][cc + 0] = w4.x; lds[row][cc + 1] = w4.y;
      lds[row][cc + 2] = w4.z; lds[row][cc + 3] = w4.w;
    }
    __syncthreads();
#pragma unroll
    for (int i = 0; i < 4; ++i) {
      int nrow = i * 16 + rr;
      ushort4 h;
      h.x = f2bf(lds[cc + 0][nrow]); h.y = f2bf(lds[cc + 1][nrow]);
      h.z = f2bf(lds[cc + 2][nrow]); h.w = f2bf(lds[cc + 3][nrow]);
      *(ushort4*)(WtB + (size_t)(n0 + nrow) * K_TOT + k0 + cc) = h;
    }
  } else if (bid < 2304) {
    // ===== job C: lbT[aid][n][r] = bf16(lora_b[aid][r][n]) (SCALING=1) =====
    int idx = (bid - 2048) * 256 + t;
    int aid = idx >> 12;
    int n = idx & 4095;
    unsigned short o[16];
#pragma unroll
    for (int r = 0; r < 16; ++r)
      o[r] = f2bf(lora_b[((size_t)aid * 16 + r) * N_TOT + n]);
    ushort4* dst = (ushort4*)(lbT + ((size_t)aid * N_TOT + n) * 16);
#pragma unroll
    for (int q = 0; q < 4; ++q) {
      ushort4 h; h.x = o[q*4+0]; h.y = o[q*4+1]; h.z = o[q*4+2]; h.w = o[q*4+3];
      dst[q] = h;
    }
  } else {
    // ===== job D: low_rank[row][r] = sum_k x[row][k]*lora_a[aid][k][r] =====
    // 256 blocks x 64 rows; MFMA; x f32 read directly (fq-groups coalesce
    // to 128B lines); lora_a transposed to LDS (padded rows, bank-spread).
    const int blk = bid - 2304;
    const int row0 = blk * 64;
    const int aid = aids[blk >> 3];   // 8 blocks per sample (S=512)
    unsigned short* At = (unsigned short*)prep_smem;  // [16][AT_LDE]

    const float* Asrc = lora_a + (size_t)aid * (K_TOT * R_LORA);
#pragma unroll
    for (int it = 0; it < 16; ++it) {
      int i = it * 256 + t;           // float4 over [1024 k][4 r-groups]
      float4 v = ((const float4*)Asrc)[i];
      int k = i >> 2;
      int r0 = (i & 3) * 4;
      At[(r0 + 0) * AT_LDE + k] = f2bf(v.x);
      At[(r0 + 1) * AT_LDE + k] = f2bf(v.y);
      At[(r0 + 2) * AT_LDE + k] = f2bf(v.z);
      At[(r0 + 3) * AT_LDE + k] = f2bf(v.w);
    }
    __syncthreads();

    const int lane = t & 63;
    const int w = t >> 6;             // wave -> rows w*16..w*16+15
    const int fr = lane & 15, fq = lane >> 4;
    const float* xrow = x + (size_t)(row0 + w * 16 + fr) * K_TOT + fq * 8;
    const unsigned short* bBase = At + fr * AT_LDE + fq * 8;

    f32x4_t acc = (f32x4_t){0.f, 0.f, 0.f, 0.f};
#pragma unroll 4
    for (int kt = 0; kt < 32; ++kt) {
      float4 u0 = *(const float4*)(xrow + kt * 32);
      float4 u1 = *(const float4*)(xrow + kt * 32 + 4);
      bf16x8_t af;
      af[0] = (short)f2bf(u0.x); af[1] = (short)f2bf(u0.y);
      af[2] = (short)f2bf(u0.z); af[3] = (short)f2bf(u0.w);
      af[4] = (short)f2bf(u1.x); af[5] = (short)f2bf(u1.y);
      af[6] = (short)f2bf(u1.z); af[7] = (short)f2bf(u1.w);
      bf16x8_t bfr = *(const bf16x8_t*)(bBase + kt * 32);
      acc = __builtin_amdgcn_mfma_f32_16x16x32_bf16(af, bfr, acc, 0, 0, 0);
    }
    int gm0 = row0 + w * 16 + fq * 4;
#pragma unroll
    for (int q = 0; q < 4; ++q)
      lrB[(size_t)(gm0 + q) * R_LORA + fr] = f2bf(acc[q]);
  }
}

// ---------- persistent main GEMM: single-phase K-step (R11, proven) ----------
#define STAGE_HALF(gbase, koff, ldsbase)                                   \
  do {                                                                     \
    gload_lds16((const char*)(gbase) + (koff), (ldsbase) + t * 16);        \
    gload_lds16((const char*)(gbase) + 64 * 2048 + (koff),                 \
                (ldsbase) + 8192 + t * 16);                                \
  } while (0)

#define MM(AS, BS, MH, NH)                                                 \
  do {                                                                     \
    __builtin_amdgcn_s_setprio(1);                                         \
    _Pragma("unroll") for (int ks = 0; ks < 2; ++ks)                       \
      _Pragma("unroll") for (int m = 0; m < 4; ++m)                        \
        _Pragma("unroll") for (int n = 0; n < 2; ++n)                      \
          acc[(MH) * 4 + m][(NH) * 2 + n] =                                \
              __builtin_amdgcn_mfma_f32_16x16x32_bf16(                     \
                  AS[m][ks], BS[n][ks],                                    \
                  acc[(MH) * 4 + m][(NH) * 2 + n], 0, 0, 0);               \
    __builtin_amdgcn_s_setprio(0);                                         \
  } while (0)

__global__ __launch_bounds__(512, 2) void gemm_kernel(
    const unsigned short* __restrict__ xB, const unsigned short* __restrict__ WtB,
    const unsigned short* __restrict__ lrB, const unsigned short* __restrict__ lbT,
    const float* __restrict__ bias, const int* __restrict__ aids,
    float* __restrict__ out) {
  // LDS: 2 buffers x { A0 | A1 | B0 | B1 } x 16 KB = 128 KB
  __shared__ char smem[131072];

  // 256 blocks, 1/CU. Fixed tn (B-panel L2-resident per XCD),
  // 4 consecutive tm tiles (A streamed exactly once).
  const int orig = blockIdx.x;
  const int xcd = orig & 7;
  const int j = orig >> 3;             // 0..31
  const int tn = xcd * 2 + (j & 1);    // 0..15
  const int tmg = j >> 1;              // 0..15; tm = tmg*4 + (s>>4)

  const int t = threadIdx.x;
  const int lane = t & 63;
  const int wid = t >> 6;
  const int wr = wid >> 2;        // 0..1 : A half
  const int wc = wid & 3;         // 0..3 : 64-col band
  const int fr = lane & 15, fq = lane >> 4;

  const int laneA = fr * 128 + (((fq << 4) ^ ((fr & 7) << 4)));
  const int waveAoff = wr * 16384;
  const int waveBoff = 32768 + (wc >> 1) * 16384 + (wc & 1) * 8192;

  // staging source pointers (pre-swizzled byte-in-row)
  const int srow = t >> 3;
  const int sb = (((t & 7) ^ (srow & 7)) << 4);
  const char* pAbase = (const char*)xB + (size_t)(tmg * 1024 + srow) * 2048 + sb;
  const char* pBpanel = (const char*)WtB + (size_t)(tn * 256 + srow) * 2048 + sb;

  f32x4_t acc[8][4];
#pragma unroll
  for (int m = 0; m < 8; ++m)
#pragma unroll
    for (int n = 0; n < 4; ++n) acc[m][n] = (f32x4_t){0.f, 0.f, 0.f, 0.f};

  // ---- prologue: stage step 0 into buffer 0 ----
  STAGE_HALF(pAbase, 0, smem + 0);
  STAGE_HALF(pAbase + (size_t)128 * 2048, 0, smem + 16384);
  STAGE_HALF(pBpanel, 0, smem + 32768);
  STAGE_HALF(pBpanel + (size_t)128 * 2048, 0, smem + 49152);
  __syncthreads();

#pragma unroll 1
  for (int s = 0; s < NSTEP; ++s) {
    char* base = smem + ((s & 1) << 16);
    char* nbase = smem + (((s + 1) & 1) << 16);
    char* bufA = base + waveAoff;
    char* bufB = base + waveBoff;

    // stage step s+1 into the other buffer (full K-step of latency to hide)
    const int u1 = s + 1;
    if (u1 < NSTEP) {
      const char* pA1 = pAbase + (size_t)(u1 >> 4) * (256 * 2048);
      const int k1 = (u1 & 15) * 128;
      STAGE_HALF(pA1, k1, nbase + 0);
      STAGE_HALF(pA1 + (size_t)128 * 2048, k1, nbase + 16384);
      STAGE_HALF(pBpanel, k1, nbase + 32768);
      STAGE_HALF(pBpanel + (size_t)128 * 2048, k1, nbase + 49152);
    }

    // issue all fragment loads; compiler staggers lgkmcnt waits per cluster
    bf16x8_t a0F[4][2], a1F[4][2], b0F[2][2], b1F[2][2];
#pragma unroll
    for (int n = 0; n < 2; ++n)
#pragma unroll
      for (int ks = 0; ks < 2; ++ks)
        b0F[n][ks] = *(const bf16x8_t*)(bufB + n * 2048 + (laneA ^ (ks << 6)));
#pragma unroll
    for (int m = 0; m < 4; ++m)
#pragma unroll
      for (int ks = 0; ks < 2; ++ks)
        a0F[m][ks] = *(const bf16x8_t*)(bufA + m * 2048 + (laneA ^ (ks << 6)));
#pragma unroll
    for (int n = 0; n < 2; ++n)
#pragma unroll
      for (int ks = 0; ks < 2; ++ks)
        b1F[n][ks] = *(const bf16x8_t*)(bufB + 4096 + n * 2048 + (laneA ^ (ks << 6)));
#pragma unroll
    for (int m = 0; m < 4; ++m)
#pragma unroll
      for (int ks = 0; ks < 2; ++ks)
        a1F[m][ks] = *(const bf16x8_t*)(bufA + 8192 + m * 2048 + (laneA ^ (ks << 6)));

    MM(a0F, b0F, 0, 0);
    MM(a0F, b1F, 0, 1);
    MM(a1F, b1F, 1, 1);
    MM(a1F, b0F, 1, 0);

    // ---- per-tile epilogue: LoRA + bias + store, reset acc ----
    if ((s & 15) == 15) {
      const int tm = tmg * 4 + (s >> 4);
      const int aid = aids[tm >> 1];  // 256 rows = half a sample (S=512)
      bf16x8_t z8 = (bf16x8_t){0, 0, 0, 0, 0, 0, 0, 0};
      bf16x8_t lrf[8], lbf[4];
#pragma unroll
      for (int m = 0; m < 8; ++m) lrf[m] = z8;
#pragma unroll
      for (int n = 0; n < 4; ++n) lbf[n] = z8;
      if (fq < 2) {
#pragma unroll
        for (int m = 0; m < 8; ++m)
          lrf[m] = *(const bf16x8_t*)(lrB + (size_t)(tm * 256 + wr * 128 + m * 16 + fr) * R_LORA + fq * 8);
#pragma unroll
        for (int n = 0; n < 4; ++n)
          lbf[n] = *(const bf16x8_t*)(lbT + ((size_t)aid * N_TOT + tn * 256 + wc * 64 + n * 16 + fr) * R_LORA + fq * 8);
      }
#pragma unroll
      for (int m = 0; m < 8; ++m)
#pragma unroll
        for (int n = 0; n < 4; ++n)
          acc[m][n] = __builtin_amdgcn_mfma_f32_16x16x32_bf16(lrf[m], lbf[n], acc[m][n], 0, 0, 0);

#pragma unroll
      for (int n = 0; n < 4; ++n) {
        int gn = tn * 256 + wc * 64 + n * 16 + fr;
        float bv = bias[gn];
#pragma unroll
        for (int m = 0; m < 8; ++m) {
          int gm0 = tm * 256 + wr * 128 + m * 16 + fq * 4;
          float* op = out + (size_t)gm0 * N_TOT + gn;
#pragma unroll
          for (int q = 0; q < 4; ++q) op[(size_t)q * N_TOT] = acc[m][n][q] + bv;
        }
      }
#pragma unroll
      for (int m = 0; m < 8; ++m)
#pragma unroll
        for (int n = 0; n < 4; ++n) acc[m][n] = (f32x4_t){0.f, 0.f, 0.f, 0.f};
    }

    // single barrier per step: drains stages (issued a full step ago) + syncs
    __syncthreads();
  }
}

extern "C" void kernel_launch(void* const* d_in, const int* in_sizes, int n_in,
                              void* d_out, int out_size, void* d_ws, size_t ws_size,
                              hipStream_t stream) {
  const float* x      = (const float*)d_in[0];
  const int*   aids   = (const int*)d_in[1];
  const float* W      = (const float*)d_in[2];
  const float* bias   = (const float*)d_in[3];
  const float* lora_a = (const float*)d_in[4];
  const float* lora_b = (const float*)d_in[5];
  float* out = (float*)d_out;

  char* ws = (char*)d_ws;
  unsigned short* xB  = (unsigned short*)(ws);                                   // 32 MB
  unsigned short* WtB = (unsigned short*)(ws + (size_t)32 * 1024 * 1024);        //  8 MB
  unsigned short* lrB = (unsigned short*)(ws + (size_t)40 * 1024 * 1024);        // 512 KB
  unsigned short* lbT = (unsigned short*)(ws + (size_t)41 * 1024 * 1024);        //  2 MB

  prep_kernel<<<2560, 256, 0, stream>>>(x, W, lora_a, lora_b, aids, xB, WtB, lrB, lbT);
  gemm_kernel<<<256, 512, 0, stream>>>(xB, WtB, lrB, lbT, bias, aids, out);
}

// Round 13
// 202.879 us; speedup vs baseline: 1.0500x; 1.0500x over previous
//
#include <hip/hip_runtime.h>

// ---------- problem constants ----------
#define M_TOT 16384   // B*S = 32*512
#define N_TOT 4096    // OUT
#define K_TOT 1024    // IN
#define R_LORA 16
#define NSTEP 64      // 4 tm-tiles x 16 K-tiles, persistent single-phase pipeline

typedef __attribute__((ext_vector_type(8))) short bf16x8_t;
typedef __attribute__((ext_vector_type(4))) float f32x4_t;

__device__ __forceinline__ unsigned short f2bf(float f) {
  unsigned u = __builtin_bit_cast(unsigned, f);
  u += 0x7FFFu + ((u >> 16) & 1u);
  return (unsigned short)(u >> 16);
}

__device__ __forceinline__ void gload_lds16(const void* g, void* l) {
  __builtin_amdgcn_global_load_lds(
      (const __attribute__((address_space(1))) unsigned int*)g,
      (__attribute__((address_space(3))) unsigned int*)l, 16, 0, 0);
}

// ---------- fused prep: x->bf16, W->Wt bf16, lora_a/b repack (R11-proven) ----------
__global__ __launch_bounds__(256) void prep_kernel(const float* __restrict__ x,
                                                   const float* __restrict__ W,
                                                   const float* __restrict__ lora_a,
                                                   const float* __restrict__ lora_b,
                                                   unsigned short* __restrict__ xB,
                                                   unsigned short* __restrict__ WtB,
                                                   unsigned short* __restrict__ AtB,
                                                   unsigned short* __restrict__ lbT) {
  __shared__ float lds[64][65];
  const int bid = blockIdx.x;
  const int t = threadIdx.x;
  if (bid < 1024) {
    size_t i = (size_t)bid * 256 + t;
    const size_t stride = (size_t)1024 * 256;
    const size_t n4 = (size_t)M_TOT * K_TOT / 4;
    for (; i < n4; i += stride) {
      float4 v = ((const float4*)x)[i];
      ushort4 h;
      h.x = f2bf(v.x); h.y = f2bf(v.y); h.z = f2bf(v.z); h.w = f2bf(v.w);
      ((ushort4*)xB)[i] = h;
    }
  } else if (bid < 2048) {
    const int v = bid - 1024;
    const int k0 = (v & 15) * 64;
    const int n0 = (v >> 4) * 64;
    const int rr = t >> 4;
    const int cc = (t & 15) * 4;
#pragma unroll
    for (int i = 0; i < 4; ++i) {
      int row = i * 16 + rr;
      float4 w4 = *(const float4*)(W + (size_t)(k0 + row) * N_TOT + n0 + cc);
      lds[row][cc + 0] = w4.x; lds[row][cc + 1] = w4.y;
      lds[row][cc + 2] = w4.z; lds[row][cc + 3] = w4.w;
    }
    __syncthreads();
#pragma unroll
    for (int i = 0; i < 4; ++i) {
      int nrow = i * 16 + rr;
      ushort4 h;
      h.x = f2bf(lds[cc + 0][nrow]); h.y = f2bf(lds[cc + 1][nrow]);
      h.z = f2bf(lds[cc + 2][nrow]); h.w = f2bf(lds[cc + 3][nrow]);
      *(ushort4*)(WtB + (size_t)(n0 + nrow) * K_TOT + k0 + cc) = h;
    }
  } else {
    const int b2 = bid - 2048;
    if (b2 < 64) {
      int idx = b2 * 256 + t;
      int aid = idx >> 10;
      int k = idx & 1023;
      const float* src = lora_a + (size_t)idx * 16;
#pragma unroll
      for (int q = 0; q < 4; ++q) {
        float4 v4 = ((const float4*)src)[q];
#pragma unroll
        for (int j = 0; j < 4; ++j) {
          int r = q * 4 + j;
          float val = (j == 0) ? v4.x : (j == 1) ? v4.y : (j == 2) ? v4.z : v4.w;
          AtB[(((size_t)aid * 16 + r) << 10) + k] = f2bf(val);
        }
      }
    } else {
      int idx = (b2 - 64) * 256 + t;
      int aid = idx >> 12;
      int n = idx & 4095;
      unsigned short o[16];
#pragma unroll
      for (int r = 0; r < 16; ++r)
        o[r] = f2bf(lora_b[((size_t)aid * 16 + r) * N_TOT + n]);
      ushort4* dst = (ushort4*)(lbT + ((size_t)aid * N_TOT + n) * 16);
#pragma unroll
      for (int q = 0; q < 4; ++q) {
        ushort4 h; h.x = o[q*4+0]; h.y = o[q*4+1]; h.z = o[q*4+2]; h.w = o[q*4+3];
        dst[q] = h;
      }
    }
  }
}

// ---------- low_rank: 256 blocks x 64 rows (1 block/CU; also warms xB) ----------
__global__ __launch_bounds__(256) void lowrank_kernel(const unsigned short* __restrict__ xB,
                                                      const unsigned short* __restrict__ AtB,
                                                      const int* __restrict__ aids,
                                                      unsigned short* __restrict__ lrB) {
  __shared__ char As[64 * 128];   // 8 KB: 64 rows x 64 bf16 (swizzled)
  const int blk = blockIdx.x;     // 0..255
  const int t = threadIdx.x;
  const int lane = t & 63;
  const int w = t >> 6;           // wave 0..3 -> rows w*16..w*16+15
  const int fr = lane & 15, fq = lane >> 4;
  const int aid = aids[blk >> 3]; // 64 rows; 8 blocks per sample (S=512)

  const unsigned short* aSrc[2];
  char* aDst[2];
#pragma unroll
  for (int r = 0; r < 2; ++r) {
    int off = (r * 256 + t) * 16;
    int row = off >> 7, cb = off & 127;
    int sb = cb ^ ((row & 7) << 4);
    aSrc[r] = xB + (size_t)(blk * 64 + row) * K_TOT + (sb >> 1);
    aDst[r] = As + off;
  }
  const unsigned short* bBase = AtB + ((size_t)aid * 16 + fr) * K_TOT + fq * 8;

  f32x4_t acc = (f32x4_t){0.f, 0.f, 0.f, 0.f};

  for (int kt = 0; kt < 16; ++kt) {
#pragma unroll
    for (int r = 0; r < 2; ++r) gload_lds16(aSrc[r] + kt * 64, aDst[r]);
    __syncthreads();
#pragma unroll
    for (int ks = 0; ks < 2; ++ks) {
      bf16x8_t bfr = *(const bf16x8_t*)(bBase + kt * 64 + ks * 32);
      int row = w * 16 + fr;
      int cb = ks * 64 + fq * 16;
      bf16x8_t af = *(const bf16x8_t*)(As + row * 128 + (cb ^ ((row & 7) << 4)));
      acc = __builtin_amdgcn_mfma_f32_16x16x32_bf16(af, bfr, acc, 0, 0, 0);
    }
    __syncthreads();
  }
  {
    int gm0 = blk * 64 + w * 16 + fq * 4;
#pragma unroll
    for (int q = 0; q < 4; ++q)
      lrB[(size_t)(gm0 + q) * R_LORA + fr] = f2bf(acc[q]);
  }
}

// ---------- persistent main GEMM: single-phase K-step ----------
// R11 structure; setprio REMOVED (T5/m190: null-to-negative on lockstep GEMM).
#define STAGE_HALF(gbase, koff, ldsbase)                                   \
  do {                                                                     \
    gload_lds16((const char*)(gbase) + (koff), (ldsbase) + t * 16);        \
    gload_lds16((const char*)(gbase) + 64 * 2048 + (koff),                 \
                (ldsbase) + 8192 + t * 16);                                \
  } while (0)

#define MM(AS, BS, MH, NH)                                                 \
  do {                                                                     \
    _Pragma("unroll") for (int ks = 0; ks < 2; ++ks)                       \
      _Pragma("unroll") for (int m = 0; m < 4; ++m)                        \
        _Pragma("unroll") for (int n = 0; n < 2; ++n)                      \
          acc[(MH) * 4 + m][(NH) * 2 + n] =                                \
              __builtin_amdgcn_mfma_f32_16x16x32_bf16(                     \
                  AS[m][ks], BS[n][ks],                                    \
                  acc[(MH) * 4 + m][(NH) * 2 + n], 0, 0, 0);               \
  } while (0)

__global__ __launch_bounds__(512, 2) void gemm_kernel(
    const unsigned short* __restrict__ xB, const unsigned short* __restrict__ WtB,
    const unsigned short* __restrict__ lrB, const unsigned short* __restrict__ lbT,
    const float* __restrict__ bias, const int* __restrict__ aids,
    float* __restrict__ out) {
  // LDS: 2 buffers x { A0 | A1 | B0 | B1 } x 16 KB = 128 KB
  __shared__ char smem[131072];

  // 256 blocks, 1/CU. Fixed tn (B-panel L2-resident per XCD),
  // 4 consecutive tm tiles (A streamed exactly once).
  const int orig = blockIdx.x;
  const int xcd = orig & 7;
  const int j = orig >> 3;             // 0..31
  const int tn = xcd * 2 + (j & 1);    // 0..15
  const int tmg = j >> 1;              // 0..15; tm = tmg*4 + (s>>4)

  const int t = threadIdx.x;
  const int lane = t & 63;
  const int wid = t >> 6;
  const int wr = wid >> 2;        // 0..1 : A half
  const int wc = wid & 3;         // 0..3 : 64-col band
  const int fr = lane & 15, fq = lane >> 4;

  const int laneA = fr * 128 + (((fq << 4) ^ ((fr & 7) << 4)));
  const int waveAoff = wr * 16384;
  const int waveBoff = 32768 + (wc >> 1) * 16384 + (wc & 1) * 8192;

  // staging source pointers (pre-swizzled byte-in-row)
  const int srow = t >> 3;
  const int sb = (((t & 7) ^ (srow & 7)) << 4);
  const char* pAbase = (const char*)xB + (size_t)(tmg * 1024 + srow) * 2048 + sb;
  const char* pBpanel = (const char*)WtB + (size_t)(tn * 256 + srow) * 2048 + sb;

  f32x4_t acc[8][4];
#pragma unroll
  for (int m = 0; m < 8; ++m)
#pragma unroll
    for (int n = 0; n < 4; ++n) acc[m][n] = (f32x4_t){0.f, 0.f, 0.f, 0.f};

  // ---- prologue: stage step 0 into buffer 0 ----
  STAGE_HALF(pAbase, 0, smem + 0);
  STAGE_HALF(pAbase + (size_t)128 * 2048, 0, smem + 16384);
  STAGE_HALF(pBpanel, 0, smem + 32768);
  STAGE_HALF(pBpanel + (size_t)128 * 2048, 0, smem + 49152);
  __syncthreads();

#pragma unroll 1
  for (int s = 0; s < NSTEP; ++s) {
    char* base = smem + ((s & 1) << 16);
    char* nbase = smem + (((s + 1) & 1) << 16);
    char* bufA = base + waveAoff;
    char* bufB = base + waveBoff;

    // stage step s+1 into the other buffer (full K-step of latency to hide)
    const int u1 = s + 1;
    if (u1 < NSTEP) {
      const char* pA1 = pAbase + (size_t)(u1 >> 4) * (256 * 2048);
      const int k1 = (u1 & 15) * 128;
      STAGE_HALF(pA1, k1, nbase + 0);
      STAGE_HALF(pA1 + (size_t)128 * 2048, k1, nbase + 16384);
      STAGE_HALF(pBpanel, k1, nbase + 32768);
      STAGE_HALF(pBpanel + (size_t)128 * 2048, k1, nbase + 49152);
    }

    // issue all fragment loads; compiler staggers lgkmcnt waits per cluster
    bf16x8_t a0F[4][2], a1F[4][2], b0F[2][2], b1F[2][2];
#pragma unroll
    for (int n = 0; n < 2; ++n)
#pragma unroll
      for (int ks = 0; ks < 2; ++ks)
        b0F[n][ks] = *(const bf16x8_t*)(bufB + n * 2048 + (laneA ^ (ks << 6)));
#pragma unroll
    for (int m = 0; m < 4; ++m)
#pragma unroll
      for (int ks = 0; ks < 2; ++ks)
        a0F[m][ks] = *(const bf16x8_t*)(bufA + m * 2048 + (laneA ^ (ks << 6)));
#pragma unroll
    for (int n = 0; n < 2; ++n)
#pragma unroll
      for (int ks = 0; ks < 2; ++ks)
        b1F[n][ks] = *(const bf16x8_t*)(bufB + 4096 + n * 2048 + (laneA ^ (ks << 6)));
#pragma unroll
    for (int m = 0; m < 4; ++m)
#pragma unroll
      for (int ks = 0; ks < 2; ++ks)
        a1F[m][ks] = *(const bf16x8_t*)(bufA + 8192 + m * 2048 + (laneA ^ (ks << 6)));

    MM(a0F, b0F, 0, 0);
    MM(a0F, b1F, 0, 1);
    MM(a1F, b1F, 1, 1);
    MM(a1F, b0F, 1, 0);

    // ---- per-tile epilogue: LoRA + bias + store, reset acc ----
    if ((s & 15) == 15) {
      const int tm = tmg * 4 + (s >> 4);
      const int aid = aids[tm >> 1];  // 256 rows = half a sample (S=512)
      bf16x8_t z8 = (bf16x8_t){0, 0, 0, 0, 0, 0, 0, 0};
      bf16x8_t lrf[8], lbf[4];
#pragma unroll
      for (int m = 0; m < 8; ++m) lrf[m] = z8;
#pragma unroll
      for (int n = 0; n < 4; ++n) lbf[n] = z8;
      if (fq < 2) {
#pragma unroll
        for (int m = 0; m < 8; ++m)
          lrf[m] = *(const bf16x8_t*)(lrB + (size_t)(tm * 256 + wr * 128 + m * 16 + fr) * R_LORA + fq * 8);
#pragma unroll
        for (int n = 0; n < 4; ++n)
          lbf[n] = *(const bf16x8_t*)(lbT + ((size_t)aid * N_TOT + tn * 256 + wc * 64 + n * 16 + fr) * R_LORA + fq * 8);
      }
#pragma unroll
      for (int m = 0; m < 8; ++m)
#pragma unroll
        for (int n = 0; n < 4; ++n)
          acc[m][n] = __builtin_amdgcn_mfma_f32_16x16x32_bf16(lrf[m], lbf[n], acc[m][n], 0, 0, 0);

#pragma unroll
      for (int n = 0; n < 4; ++n) {
        int gn = tn * 256 + wc * 64 + n * 16 + fr;
        float bv = bias[gn];
#pragma unroll
        for (int m = 0; m < 8; ++m) {
          int gm0 = tm * 256 + wr * 128 + m * 16 + fq * 4;
          float* op = out + (size_t)gm0 * N_TOT + gn;
#pragma unroll
          for (int q = 0; q < 4; ++q) op[(size_t)q * N_TOT] = acc[m][n][q] + bv;
        }
      }
#pragma unroll
      for (int m = 0; m < 8; ++m)
#pragma unroll
        for (int n = 0; n < 4; ++n) acc[m][n] = (f32x4_t){0.f, 0.f, 0.f, 0.f};
    }

    // single barrier per step: drains stages (issued a full step ago) + syncs
    __syncthreads();
  }
}

extern "C" void kernel_launch(void* const* d_in, const int* in_sizes, int n_in,
                              void* d_out, int out_size, void* d_ws, size_t ws_size,
                              hipStream_t stream) {
  const float* x      = (const float*)d_in[0];
  const int*   aids   = (const int*)d_in[1];
  const float* W      = (const float*)d_in[2];
  const float* bias   = (const float*)d_in[3];
  const float* lora_a = (const float*)d_in[4];
  const float* lora_b = (const float*)d_in[5];
  float* out = (float*)d_out;

  char* ws = (char*)d_ws;
  unsigned short* xB  = (unsigned short*)(ws);                                   // 32 MB
  unsigned short* WtB = (unsigned short*)(ws + (size_t)32 * 1024 * 1024);        //  8 MB
  unsigned short* lrB = (unsigned short*)(ws + (size_t)40 * 1024 * 1024);        // 512 KB
  unsigned short* AtB = (unsigned short*)(ws + (size_t)40 * 1024 * 1024 + 512 * 1024); // 512 KB
  unsigned short* lbT = (unsigned short*)(ws + (size_t)41 * 1024 * 1024);        //  2 MB

  prep_kernel<<<2368, 256, 0, stream>>>(x, W, lora_a, lora_b, xB, WtB, AtB, lbT);
  lowrank_kernel<<<256, 256, 0, stream>>>(xB, AtB, aids, lrB);
  gemm_kernel<<<256, 512, 0, stream>>>(xB, WtB, lrB, lbT, bias, aids, out);
}